// Round 1
// baseline (360.669 us; speedup 1.0000x reference)
//
#include <hip/hip_runtime.h>
#include <math.h>

// Constants matching the reference
#define LOG_SQRT_2PI 0.9189385332046727f   // 0.5*ln(2*pi)

// ---------------------------------------------------------------------------
// Kernel A: compute weight[s,j] = mu[j] + softplus(rho[j]) * eps[s,j] into ws,
// and reduce the two scalar log-densities. Single block (S*J = 16K elems).
// ---------------------------------------------------------------------------
__global__ __launch_bounds__(1024)
void bel_prep_reduce(const float* __restrict__ mu,
                     const float* __restrict__ rho,
                     const float* __restrict__ eps,
                     float* __restrict__ weight,       // [S*J] scratch
                     float* __restrict__ out_scalars,  // d_out + S*B*J: {log_prior, log_var_post}
                     int S, int J) {
    const int n = S * J;
    double acc_lvp = 0.0;   // log variational posterior
    double acc_lpr = 0.0;   // log prior

    const float log_half = logf(0.5f);
    const float log_sigma2 = logf(0.002f);
    const float inv_2s2_2 = 1.0f / (2.0f * 0.002f * 0.002f);  // 125000

    for (int idx = threadIdx.x; idx < n; idx += blockDim.x) {
        const int j = idx % J;
        const float m = mu[j];
        const float r = rho[j];
        const float e = eps[idx];

        const float sigma = log1pf(expf(r));       // softplus
        const float w = m + sigma * e;
        weight[idx] = w;

        // variational posterior logpdf(w; m, sigma)
        const float d = w - m;
        acc_lvp += (double)(-LOG_SQRT_2PI - logf(sigma)
                            - (d * d) / (2.0f * sigma * sigma));

        // scale-mixture prior, stable logaddexp
        const float w2 = w * w;
        const float lp1 = -LOG_SQRT_2PI - 0.5f * w2 + log_half;          // sigma1 = 1
        const float lp2 = -LOG_SQRT_2PI - log_sigma2 - w2 * inv_2s2_2 + log_half;
        const float mx = fmaxf(lp1, lp2);
        const float mn = fminf(lp1, lp2);
        acc_lpr += (double)(mx + log1pf(expf(mn - mx)));
    }

    // wave (64-lane) shuffle reduce
    for (int off = 32; off > 0; off >>= 1) {
        acc_lvp += __shfl_down(acc_lvp, off, 64);
        acc_lpr += __shfl_down(acc_lpr, off, 64);
    }

    __shared__ double s_lvp[16];
    __shared__ double s_lpr[16];
    const int wid = threadIdx.x >> 6;
    const int lane = threadIdx.x & 63;
    if (lane == 0) { s_lvp[wid] = acc_lvp; s_lpr[wid] = acc_lpr; }
    __syncthreads();
    if (threadIdx.x == 0) {
        double lvp = 0.0, lpr = 0.0;
        const int nw = blockDim.x >> 6;
        for (int i = 0; i < nw; ++i) { lvp += s_lvp[i]; lpr += s_lpr[i]; }
        out_scalars[0] = (float)lpr;   // log_prior (second return value)
        out_scalars[1] = (float)lvp;   // log_variational_posterior (third)
    }
}

// ---------------------------------------------------------------------------
// Kernel B: out[s,b,j] = x[b,j] * weight[s,j].  float4 per thread, one x read,
// S coalesced writes. Memory-bound: 64MB read + 256MB write.
// ---------------------------------------------------------------------------
__global__ __launch_bounds__(256)
void bel_scale(const float4* __restrict__ x4,
               const float4* __restrict__ w4,     // [S * J/4]
               float4* __restrict__ o4,
               long long total4,                  // B*J/4
               int Jv,                            // J/4
               int S) {
    long long idx = (long long)blockIdx.x * blockDim.x + threadIdx.x;
    const long long stride = (long long)gridDim.x * blockDim.x;
    for (; idx < total4; idx += stride) {
        const int jv = (int)(idx % Jv);
        const float4 xv = x4[idx];
        #pragma unroll 4
        for (int s = 0; s < S; ++s) {
            const float4 wv = w4[(long long)s * Jv + jv];
            float4 ov;
            ov.x = xv.x * wv.x;
            ov.y = xv.y * wv.y;
            ov.z = xv.z * wv.z;
            ov.w = xv.w * wv.w;
            o4[(long long)s * total4 + idx] = ov;
        }
    }
}

extern "C" void kernel_launch(void* const* d_in, const int* in_sizes, int n_in,
                              void* d_out, int out_size, void* d_ws, size_t ws_size,
                              hipStream_t stream) {
    const float* x   = (const float*)d_in[0];
    const float* mu  = (const float*)d_in[1];
    const float* rho = (const float*)d_in[2];
    const float* eps = (const float*)d_in[3];
    // d_in[4] = n_samples (scalar), but we derive S from sizes.

    const int J = in_sizes[1];
    const int B = in_sizes[0] / J;
    const int S = in_sizes[3] / J;

    float* out = (float*)d_out;
    float* weight = (float*)d_ws;                       // S*J floats
    float* out_scalars = out + (long long)S * B * J;    // trailing 2 floats

    // Kernel A: weights + scalar reductions (tiny)
    bel_prep_reduce<<<1, 1024, 0, stream>>>(mu, rho, eps, weight, out_scalars, S, J);

    // Kernel B: the 320MB streaming multiply
    const long long total4 = (long long)B * J / 4;
    const int Jv = J / 4;
    const int block = 256;
    long long blocks = (total4 + block - 1) / block;
    if (blocks > 65535LL * 64) blocks = 65535LL * 64;   // safety cap, grid-stride covers rest
    bel_scale<<<(int)blocks, block, 0, stream>>>(
        (const float4*)x, (const float4*)weight, (float4*)out, total4, Jv, S);
}

// Round 3
// 336.534 us; speedup vs baseline: 1.0717x; 1.0717x over previous
//
#include <hip/hip_runtime.h>
#include <math.h>

#define LOG_SQRT_2PI 0.9189385332046727f   // 0.5*ln(2*pi)

typedef float f32x4 __attribute__((ext_vector_type(4)));   // native vector: OK for nontemporal builtins

// ---------------------------------------------------------------------------
// Reduction duty shared by fused and generic paths.
// ws layout: ws[0]=log_prior (double), ws[1]=log_var_post (double),
//            bytes [16,20) = uint completion counter. Zeroed by memset.
// ---------------------------------------------------------------------------
__device__ __forceinline__
void reduce_duty(const float* __restrict__ mu,
                 const float* __restrict__ rho,
                 const float* __restrict__ eps,
                 float* __restrict__ out_scalars,
                 double* __restrict__ ws,
                 int S, int J, int nRed)
{
    const int n = S * J;
    double lvp = 0.0, lpr = 0.0;
    const float log_half   = -0.6931471805599453f;   // ln(0.5)
    const float log_sigma2 = -6.214608098422191f;    // ln(0.002)
    const float inv_2s2_2  = 125000.0f;              // 1/(2*0.002^2)

    for (int idx = blockIdx.x * blockDim.x + threadIdx.x; idx < n;
         idx += nRed * blockDim.x) {
        const int j = idx % J;
        const float m = mu[j];
        const float r = rho[j];
        const float e = eps[idx];
        const float sg = log1pf(expf(r));        // softplus
        const float w  = m + sg * e;

        const float d = w - m;                    // = sg*e
        lvp += (double)(-LOG_SQRT_2PI - logf(sg) - (d * d) / (2.0f * sg * sg));

        const float w2  = w * w;
        const float lp1 = -LOG_SQRT_2PI - 0.5f * w2 + log_half;
        const float lp2 = -LOG_SQRT_2PI - log_sigma2 - w2 * inv_2s2_2 + log_half;
        const float mx  = fmaxf(lp1, lp2);
        const float mn  = fminf(lp1, lp2);
        lpr += (double)(mx + log1pf(expf(mn - mx)));
    }

    // wave64 shuffle reduce
    for (int off = 32; off > 0; off >>= 1) {
        lvp += __shfl_down(lvp, off, 64);
        lpr += __shfl_down(lpr, off, 64);
    }
    __shared__ double s_l[2][4];
    const int wid = threadIdx.x >> 6, lane = threadIdx.x & 63;
    if (lane == 0) { s_l[0][wid] = lvp; s_l[1][wid] = lpr; }
    __syncthreads();
    if (threadIdx.x == 0) {
        const int nw = blockDim.x >> 6;
        double bl_lvp = 0.0, bl_lpr = 0.0;
        for (int i = 0; i < nw; ++i) { bl_lvp += s_l[0][i]; bl_lpr += s_l[1][i]; }
        atomicAdd(&ws[0], bl_lpr);
        atomicAdd(&ws[1], bl_lvp);
        __threadfence();                               // release partials
        unsigned int* counter = (unsigned int*)(ws + 2);
        const unsigned int prev = atomicAdd(counter, 1u);
        if (prev == (unsigned)(nRed - 1)) {
            __threadfence();                           // acquire
            out_scalars[0] = (float)atomicAdd(&ws[0], 0.0);  // log_prior
            out_scalars[1] = (float)atomicAdd(&ws[1], 0.0);  // log_var_post
        }
    }
}

// ---------------------------------------------------------------------------
// Fused kernel, specialized S==4. Streaming: each thread owns one float4 of j,
// computes its 16 weights once in registers, loops over b-rows with ILP.
// ---------------------------------------------------------------------------
__global__ __launch_bounds__(256)
void bel_fused4(const f32x4* __restrict__ x4,
                const float* __restrict__ mu,
                const float* __restrict__ rho,
                const float* __restrict__ eps,
                f32x4* __restrict__ o4,
                float* __restrict__ out_scalars,
                double* __restrict__ ws,
                int B, int J, int jblocks, int nRed)
{
    if ((int)blockIdx.x < nRed)
        reduce_duty(mu, rho, eps, out_scalars, ws, 4, J, nRed);

    const int Jv      = J >> 2;
    const int jb      = blockIdx.x % jblocks;
    const int bstart  = blockIdx.x / jblocks;
    const int bstride = gridDim.x / jblocks;
    const int jv      = jb * blockDim.x + threadIdx.x;     // [0, Jv)
    if (jv >= Jv) return;

    const f32x4 muv  = ((const f32x4*)mu)[jv];
    const f32x4 rhov = ((const f32x4*)rho)[jv];
    f32x4 sg;
    sg.x = log1pf(expf(rhov.x));
    sg.y = log1pf(expf(rhov.y));
    sg.z = log1pf(expf(rhov.z));
    sg.w = log1pf(expf(rhov.w));

    const f32x4 e0 = ((const f32x4*)eps)[0 * Jv + jv];
    const f32x4 e1 = ((const f32x4*)eps)[1 * Jv + jv];
    const f32x4 e2 = ((const f32x4*)eps)[2 * Jv + jv];
    const f32x4 e3 = ((const f32x4*)eps)[3 * Jv + jv];

    const f32x4 w0 = muv + sg * e0;
    const f32x4 w1 = muv + sg * e1;
    const f32x4 w2 = muv + sg * e2;
    const f32x4 w3 = muv + sg * e3;

    const size_t plane = (size_t)B * Jv;   // f32x4 elems per s-plane

    #pragma unroll 4
    for (int b = bstart; b < B; b += bstride) {
        const size_t rb = (size_t)b * Jv + jv;
        const f32x4 xv = x4[rb];
        __builtin_nontemporal_store(xv * w0, &o4[0 * plane + rb]);
        __builtin_nontemporal_store(xv * w1, &o4[1 * plane + rb]);
        __builtin_nontemporal_store(xv * w2, &o4[2 * plane + rb]);
        __builtin_nontemporal_store(xv * w3, &o4[3 * plane + rb]);
    }
}

// ---------------------------------------------------------------------------
// Generic fallbacks (S != 4): reduction kernel + elementwise kernel.
// ---------------------------------------------------------------------------
__global__ __launch_bounds__(256)
void bel_reduce_gen(const float* __restrict__ mu, const float* __restrict__ rho,
                    const float* __restrict__ eps, float* __restrict__ out_scalars,
                    double* __restrict__ ws, int S, int J, int nRed)
{
    reduce_duty(mu, rho, eps, out_scalars, ws, S, J, nRed);
}

__global__ __launch_bounds__(256)
void bel_scale_gen(const f32x4* __restrict__ x4,
                   const float* __restrict__ mu, const float* __restrict__ rho,
                   const float* __restrict__ eps, f32x4* __restrict__ o4,
                   long long total4, int Jv, int B, int S)
{
    long long idx = (long long)blockIdx.x * blockDim.x + threadIdx.x;
    const long long stride = (long long)gridDim.x * blockDim.x;
    const long long plane = (long long)B * Jv;
    for (; idx < (long long)S * plane; idx += stride) {
        const int s  = (int)(idx / plane);
        const long long r = idx % plane;
        const int jv = (int)(r % Jv);
        const f32x4 muv  = ((const f32x4*)mu)[jv];
        const f32x4 rhov = ((const f32x4*)rho)[jv];
        const f32x4 ev   = ((const f32x4*)eps)[(long long)s * Jv + jv];
        const f32x4 xv   = x4[r];
        f32x4 sg;
        sg.x = log1pf(expf(rhov.x));
        sg.y = log1pf(expf(rhov.y));
        sg.z = log1pf(expf(rhov.z));
        sg.w = log1pf(expf(rhov.w));
        const f32x4 ov = xv * (muv + sg * ev);
        __builtin_nontemporal_store(ov, &o4[idx]);
    }
}

extern "C" void kernel_launch(void* const* d_in, const int* in_sizes, int n_in,
                              void* d_out, int out_size, void* d_ws, size_t ws_size,
                              hipStream_t stream) {
    const float* x   = (const float*)d_in[0];
    const float* mu  = (const float*)d_in[1];
    const float* rho = (const float*)d_in[2];
    const float* eps = (const float*)d_in[3];

    const int J = in_sizes[1];
    const int B = in_sizes[0] / J;
    const int S = in_sizes[3] / J;

    float* out = (float*)d_out;
    float* out_scalars = out + (size_t)S * B * J;   // {log_prior, log_var_post}
    double* ws = (double*)d_ws;

    // zero the two double accumulators + completion counter
    (void)hipMemsetAsync(d_ws, 0, 24, stream);

    const int nRed = 32;
    const int block = 256;
    const int Jv = J / 4;

    if (S == 4 && (Jv % block) == 0) {
        const int jblocks  = Jv / block;                  // j-tiles per row
        const int bstride  = (B < 1024) ? B : 1024;       // rows in parallel
        const int grid     = jblocks * bstride;           // 4096 for 4096x4096
        bel_fused4<<<grid, block, 0, stream>>>(
            (const f32x4*)x, mu, rho, eps, (f32x4*)out, out_scalars, ws,
            B, J, jblocks, nRed);
    } else {
        bel_reduce_gen<<<nRed, block, 0, stream>>>(mu, rho, eps, out_scalars, ws, S, J, nRed);
        const long long total4 = (long long)S * B * Jv;
        long long blocks = (total4 + block - 1) / block;
        if (blocks > 2048) blocks = 2048;
        bel_scale_gen<<<(int)blocks, block, 0, stream>>>(
            (const f32x4*)x, mu, rho, eps, (f32x4*)out, total4, Jv, B, S);
    }
}

// Round 5
// 334.706 us; speedup vs baseline: 1.0776x; 1.0055x over previous
//
#include <hip/hip_runtime.h>
#include <math.h>

#define LOG_SQRT_2PI 0.9189385332046727f   // 0.5*ln(2*pi)

typedef float f32x4 __attribute__((ext_vector_type(4)));

// ---------------------------------------------------------------------------
// Reduction duty (log_prior, log_variational_posterior over S*J elements).
// ws layout: ws[0]=log_prior (double), ws[1]=log_var_post (double),
//            bytes [16,20) = uint completion counter. Zeroed by memset.
// ---------------------------------------------------------------------------
__device__ __forceinline__
void reduce_duty(const float* __restrict__ mu,
                 const float* __restrict__ rho,
                 const float* __restrict__ eps,
                 float* __restrict__ out_scalars,
                 double* __restrict__ ws,
                 int S, int J, int nRed)
{
    const int n = S * J;
    double lvp = 0.0, lpr = 0.0;
    const float log_half   = -0.6931471805599453f;   // ln(0.5)
    const float log_sigma2 = -6.214608098422191f;    // ln(0.002)
    const float inv_2s2_2  = 125000.0f;              // 1/(2*0.002^2)

    for (int idx = blockIdx.x * blockDim.x + threadIdx.x; idx < n;
         idx += nRed * blockDim.x) {
        const int j = idx % J;
        const float m = mu[j];
        const float r = rho[j];
        const float e = eps[idx];
        const float sg = log1pf(expf(r));        // softplus
        const float w  = m + sg * e;

        const float d = w - m;                    // = sg*e
        lvp += (double)(-LOG_SQRT_2PI - logf(sg) - (d * d) / (2.0f * sg * sg));

        const float w2  = w * w;
        const float lp1 = -LOG_SQRT_2PI - 0.5f * w2 + log_half;
        const float lp2 = -LOG_SQRT_2PI - log_sigma2 - w2 * inv_2s2_2 + log_half;
        const float mx  = fmaxf(lp1, lp2);
        const float mn  = fminf(lp1, lp2);
        lpr += (double)(mx + log1pf(expf(mn - mx)));
    }

    for (int off = 32; off > 0; off >>= 1) {
        lvp += __shfl_down(lvp, off, 64);
        lpr += __shfl_down(lpr, off, 64);
    }
    __shared__ double s_l[2][4];
    const int wid = threadIdx.x >> 6, lane = threadIdx.x & 63;
    if (lane == 0) { s_l[0][wid] = lvp; s_l[1][wid] = lpr; }
    __syncthreads();
    if (threadIdx.x == 0) {
        const int nw = blockDim.x >> 6;
        double bl_lvp = 0.0, bl_lpr = 0.0;
        for (int i = 0; i < nw; ++i) { bl_lvp += s_l[0][i]; bl_lpr += s_l[1][i]; }
        atomicAdd(&ws[0], bl_lpr);
        atomicAdd(&ws[1], bl_lvp);
        __threadfence();
        unsigned int* counter = (unsigned int*)(ws + 2);
        const unsigned int prev = atomicAdd(counter, 1u);
        if (prev == (unsigned)(nRed - 1)) {
            __threadfence();
            out_scalars[0] = (float)atomicAdd(&ws[0], 0.0);  // log_prior
            out_scalars[1] = (float)atomicAdd(&ws[1], 0.0);  // log_var_post
        }
    }
}

// ---------------------------------------------------------------------------
// Fused kernel, S==4. Each thread owns TWO coalesced float4 columns
// (jv0 = tile + tid, jv1 = jv0 + blockDim): every load/store instruction is a
// fully contiguous 1KB/wave access. Regular stores (NT removed: L2
// write-combining is the 6.5TB/s path the fill kernel uses).
// ---------------------------------------------------------------------------
__global__ __launch_bounds__(256)
void bel_fused4(const f32x4* __restrict__ x4,
                const float* __restrict__ mu,
                const float* __restrict__ rho,
                const float* __restrict__ eps,
                f32x4* __restrict__ o4,
                float* __restrict__ out_scalars,
                double* __restrict__ ws,
                int B, int J, int jblocks, int bstride, int nRed)
{
    if ((int)blockIdx.x < nRed)
        reduce_duty(mu, rho, eps, out_scalars, ws, 4, J, nRed);

    const int Jv  = J >> 2;
    const int TW  = blockDim.x * 2;                 // float4 per j-tile
    const int jb  = blockIdx.x % jblocks;
    const int bstart = blockIdx.x / jblocks;
    const int jv0 = jb * TW + threadIdx.x;
    const int jv1 = jv0 + blockDim.x;

    const f32x4* muv  = (const f32x4*)mu;
    const f32x4* rhov = (const f32x4*)rho;
    const f32x4* ev   = (const f32x4*)eps;

    f32x4 w[2][4];
    #pragma unroll
    for (int c = 0; c < 2; ++c) {
        const int jv = c ? jv1 : jv0;
        const f32x4 m = muv[jv];
        const f32x4 r = rhov[jv];
        f32x4 sg;
        sg.x = log1pf(expf(r.x)); sg.y = log1pf(expf(r.y));
        sg.z = log1pf(expf(r.z)); sg.w = log1pf(expf(r.w));
        #pragma unroll
        for (int s = 0; s < 4; ++s)
            w[c][s] = m + sg * ev[s * Jv + jv];
    }

    const size_t plane = (size_t)B * Jv;            // f32x4 per s-plane

    #pragma unroll 4
    for (int b = bstart; b < B; b += bstride) {
        const size_t r0 = (size_t)b * Jv + jv0;
        const size_t r1 = (size_t)b * Jv + jv1;
        const f32x4 x0 = x4[r0];
        const f32x4 x1 = x4[r1];
        o4[0 * plane + r0] = x0 * w[0][0];
        o4[0 * plane + r1] = x1 * w[1][0];
        o4[1 * plane + r0] = x0 * w[0][1];
        o4[1 * plane + r1] = x1 * w[1][1];
        o4[2 * plane + r0] = x0 * w[0][2];
        o4[2 * plane + r1] = x1 * w[1][2];
        o4[3 * plane + r0] = x0 * w[0][3];
        o4[3 * plane + r1] = x1 * w[1][3];
    }
}

// ---------------------------------------------------------------------------
// Generic fallbacks (S != 4 or odd shapes).
// ---------------------------------------------------------------------------
__global__ __launch_bounds__(256)
void bel_reduce_gen(const float* __restrict__ mu, const float* __restrict__ rho,
                    const float* __restrict__ eps, float* __restrict__ out_scalars,
                    double* __restrict__ ws, int S, int J, int nRed)
{
    reduce_duty(mu, rho, eps, out_scalars, ws, S, J, nRed);
}

__global__ __launch_bounds__(256)
void bel_scale_gen(const f32x4* __restrict__ x4,
                   const float* __restrict__ mu, const float* __restrict__ rho,
                   const float* __restrict__ eps, f32x4* __restrict__ o4,
                   long long total4, int Jv, int B, int S)
{
    long long idx = (long long)blockIdx.x * blockDim.x + threadIdx.x;
    const long long stride = (long long)gridDim.x * blockDim.x;
    const long long plane = (long long)B * Jv;
    for (; idx < (long long)S * plane; idx += stride) {
        const int s  = (int)(idx / plane);
        const long long r = idx % plane;
        const int jv = (int)(r % Jv);
        const f32x4 muv  = ((const f32x4*)mu)[jv];
        const f32x4 rhov = ((const f32x4*)rho)[jv];
        const f32x4 evv  = ((const f32x4*)eps)[(long long)s * Jv + jv];
        const f32x4 xv   = x4[r];
        f32x4 sg;
        sg.x = log1pf(expf(rhov.x)); sg.y = log1pf(expf(rhov.y));
        sg.z = log1pf(expf(rhov.z)); sg.w = log1pf(expf(rhov.w));
        o4[idx] = xv * (muv + sg * evv);
    }
}

extern "C" void kernel_launch(void* const* d_in, const int* in_sizes, int n_in,
                              void* d_out, int out_size, void* d_ws, size_t ws_size,
                              hipStream_t stream) {
    const float* x   = (const float*)d_in[0];
    const float* mu  = (const float*)d_in[1];
    const float* rho = (const float*)d_in[2];
    const float* eps = (const float*)d_in[3];

    const int J = in_sizes[1];
    const int B = in_sizes[0] / J;
    const int S = in_sizes[3] / J;

    float* out = (float*)d_out;
    float* out_scalars = out + (size_t)S * B * J;   // {log_prior, log_var_post}
    double* ws = (double*)d_ws;

    (void)hipMemsetAsync(d_ws, 0, 24, stream);

    const int nRed = 32;
    const int block = 256;
    const int Jv = J / 4;
    const int TW = block * 2;                       // 512 float4 per j-tile

    if (S == 4 && (Jv % TW) == 0 && B >= 4) {
        const int jblocks = Jv / TW;                // 2 for J=4096
        int bstride = 1024;                         // 4 b-iterations for B=4096
        if (bstride > B) bstride = B;
        const int grid = jblocks * bstride;         // 2048 blocks
        bel_fused4<<<grid, block, 0, stream>>>(
            (const f32x4*)x, mu, rho, eps, (f32x4*)out, out_scalars, ws,
            B, J, jblocks, bstride, nRed);
    } else {
        bel_reduce_gen<<<nRed, block, 0, stream>>>(mu, rho, eps, out_scalars, ws, S, J, nRed);
        const long long total4 = (long long)S * B * Jv;
        long long blocks = (total4 + block - 1) / block;
        if (blocks > 2048) blocks = 2048;
        bel_scale_gen<<<(int)blocks, block, 0, stream>>>(
            (const f32x4*)x, mu, rho, eps, (f32x4*)out, total4, Jv, B, S);
    }
}